// Round 6
// baseline (29.683 us; speedup 1.0000x reference)
//
#include <hip/hip_runtime.h>

// CountHistogram: B=128, C=4, Q=32, D=2048, NBINS=30
// out[b,c,q,bin] = sum_d [ bin(simmat[b,c,q,d]) == bin ] * (dtoks[b,d]!=-1) * (qtoks[b,q]!=-1)
//
// Design (R5): 2 rows per wave, branchless, no barriers.
//   - dtoks -> per-lane u32 nibble mask computed ONCE per wave (rows share b):
//     bit 4j+k = (dtoks[b][4*(j*64+lane)+k] != -1). Halves dtoks VMEM, removes
//     compares from the row loop.
//   - qt==-1 rows: mask register zeroed -> all elements to dead slot 31.
//     No branch => both rows' simmat loads form one flat schedulable stream.
//   - per-row, per-wave histograms: 8 sub-hists (8-lane groups), stride 33
//     => bank(bin,g) = (bin+g) mod 32: cross-group conflict-free, same-addr
//     collisions confined to 8 lanes. No re-zero between rows.
//   - (x+1.00001f)*14.5f == ((x+1.00001f)/2)*29 bit-exactly (/2 exact, one
//     rounding each) -> one VALU op saved per element.

#define NBINS   30
#define DIM     2048
#define QDIM    32
#define CDIM    4
#define BDIM    128
#define GSTRIDE 33
#define WSTRIDE (8 * GSTRIDE)                        // 264 words per row-hist
#define ROWS    2

typedef float nfloat4 __attribute__((ext_vector_type(4)));
typedef int   nint4   __attribute__((ext_vector_type(4)));

__global__ __launch_bounds__(256, 4) void CountHistogram_kernel(
    const float* __restrict__ simmat,
    const int*   __restrict__ dtoks,
    const int*   __restrict__ qtoks,
    float*       __restrict__ out)
{
    const int tid   = threadIdx.x;
    const int wave  = tid >> 6;
    const int lane  = tid & 63;
    const int rbase = (blockIdx.x * 4 + wave) * ROWS;   // first of 2 rows
    const int b     = rbase >> 7;                        // rows of a wave share b

    __shared__ int hs[4][ROWS][WSTRIDE];                 // [wave][row][8*33]
    int* hw = &hs[wave][0][0];
    // zero 2*264 = 528 words per wave (same-wave DS ordering protects atomics)
    #pragma unroll
    for (int z = 0; z < 8; ++z) hw[z * 64 + lane] = 0;
    if (lane < 2 * WSTRIDE - 512) hw[512 + lane] = 0;

    // ---- dtoks nibble mask, once per wave ----
    const nint4* dt = (const nint4*)(dtoks + (size_t)b * DIM);
    unsigned int mask = 0;
    #pragma unroll
    for (int j = 0; j < 8; ++j) {
        const nint4 t = dt[j * 64 + lane];
        unsigned int nib = (unsigned int)(t.x != -1)
                         | ((unsigned int)(t.y != -1) << 1)
                         | ((unsigned int)(t.z != -1) << 2)
                         | ((unsigned int)(t.w != -1) << 3);
        mask |= nib << (4 * j);
    }

    const int grpoff = (lane >> 3) * GSTRIDE;            // this lane's group

    #pragma unroll
    for (int r = 0; r < ROWS; ++r) {
        const int row = rbase + r;
        const int qt  = qtoks[b * QDIM + (row & (QDIM - 1))];   // wave-uniform
        const unsigned int rm = (qt != -1) ? mask : 0u;
        int* hg = &hs[wave][r][0] + grpoff;
        const nfloat4* sm = (const nfloat4*)(simmat + (size_t)row * DIM);
        #pragma unroll
        for (int j = 0; j < 8; ++j) {
            const nfloat4 s = __builtin_nontemporal_load(&sm[j * 64 + lane]);
            const unsigned int nib = rm >> (4 * j);
            // bit-exact: ((x+1.00001f)/2.0f)*29.0f == (x+1.00001f)*14.5f
            int b0 = (int)((s.x + 1.00001f) * 14.5f);
            int b1 = (int)((s.y + 1.00001f) * 14.5f);
            int b2 = (int)((s.z + 1.00001f) * 14.5f);
            int b3 = (int)((s.w + 1.00001f) * 14.5f);
            b0 = (nib & 1u) ? b0 : 31;
            b1 = (nib & 2u) ? b1 : 31;
            b2 = (nib & 4u) ? b2 : 31;
            b3 = (nib & 8u) ? b3 : 31;
            atomicAdd(&hg[b0], 1);
            atomicAdd(&hg[b1], 1);
            atomicAdd(&hg[b2], 1);
            atomicAdd(&hg[b3], 1);
        }
    }

    // same-wave DS ordering: all atomics retired before these reads
    if (lane < NBINS) {
        #pragma unroll
        for (int r = 0; r < ROWS; ++r) {
            int sum = 0;
            #pragma unroll
            for (int g = 0; g < 8; ++g)
                sum += hs[wave][r][g * GSTRIDE + lane];
            out[(size_t)(rbase + r) * NBINS + lane] = (float)sum;
        }
    }
}

extern "C" void kernel_launch(void* const* d_in, const int* in_sizes, int n_in,
                              void* d_out, int out_size, void* d_ws, size_t ws_size,
                              hipStream_t stream) {
    const float* simmat = (const float*)d_in[0];
    // d_in[1] = dlens (unused by the reference)
    const int*   dtoks  = (const int*)d_in[2];
    const int*   qtoks  = (const int*)d_in[3];
    float*       out    = (float*)d_out;

    const int nrows = BDIM * CDIM * QDIM;                // 16384
    CountHistogram_kernel<<<nrows / (4 * ROWS), 256, 0, stream>>>(simmat, dtoks, qtoks, out);
}